// Round 5
// baseline (716.985 us; speedup 1.0000x reference)
//
#include <hip/hip_runtime.h>
#include <cstdint>
#include <cstddef>

#define BATCH 32768
#define NHID 256
#define KTOT 2048                 // NHID * 8
#define BM 64                     // batch rows per block
#define MAT_ELEMS (NHID * KTOT)   // 524288 elements per weight matrix
#define QUAD_SHORTS (16 * 64 * 32) // 32768 shorts = 64KB per chunk-QUAD of packed W
#define EPI_STRIDE 132            // floats per row in epilogue LDS (16B-aligned, pads banks)
#define SMEM_BYTES (BM * EPI_STRIDE * 4)  // 33792 >= 8 basis bufs * 4KB = 32768

typedef __attribute__((ext_vector_type(8))) short short8;
typedef __attribute__((ext_vector_type(4))) float f32x4;
typedef __attribute__((ext_vector_type(4))) int int4v;

__device__ __forceinline__ float fast_tanh(float x) {
    float e = __expf(2.0f * x);
    return 1.0f - 2.0f / (e + 1.0f);
}

__device__ __forceinline__ unsigned short f2bf(float f) {
    union { float f; unsigned u; } v; v.f = f;
    unsigned r = v.u + 0x7fffu + ((v.u >> 16) & 1u);  // RNE (prepack only)
    return (unsigned short)(r >> 16);
}

// lgkm-only barrier (CK idiom): LDS handoff without draining vmcnt —
// in-flight global B-fragment prefetches survive the barrier.
__device__ __forceinline__ void block_sync_lds() {
    asm volatile("s_waitcnt lgkmcnt(0)" ::: "memory");
    __builtin_amdgcn_s_barrier();
    asm volatile("" ::: "memory");
}

// T0..T7 of tanh(hv), packed to 8 bf16 in an int4: round-half-up + v_perm pack
__device__ __forceinline__ int4v cheb_pack(float hv) {
    float t = fast_tanh(hv);
    float t2 = t + t;
    unsigned u[8];
    union { float f; unsigned q; } c;
    c.f = 1.0f; u[0] = c.q;
    c.f = t;    u[1] = c.q;
    float Tm = 1.0f, Tc = t;
#pragma unroll
    for (int d = 2; d < 8; ++d) {
        float Tn = fmaf(t2, Tc, -Tm);   // T_d = 2t*T_{d-1} - T_{d-2}
        c.f = Tn; u[d] = c.q;
        Tm = Tc; Tc = Tn;
    }
#pragma unroll
    for (int i = 0; i < 8; ++i) u[i] += 0x8000u;   // round-half-up to bf16
    int4v p;
    p.x = (int)__builtin_amdgcn_perm(u[1], u[0], 0x07060302);
    p.y = (int)__builtin_amdgcn_perm(u[3], u[2], 0x07060302);
    p.z = (int)__builtin_amdgcn_perm(u[5], u[4], 0x07060302);
    p.w = (int)__builtin_amdgcn_perm(u[7], u[6], 0x07060302);
    return p;
}

// ---------------------------------------------------------------- RFF embed
__global__ __launch_bounds__(256) void kan_rff(
    const float* __restrict__ x, const float* __restrict__ B, float* __restrict__ h)
{
    int t = blockIdx.x * 256 + threadIdx.x;   // over BATCH*128
    int j = t & 127;
    int b = t >> 7;
    float x0 = x[b * 3 + 0], x1 = x[b * 3 + 1], x2 = x[b * 3 + 2];
    float z = x0 * B[j] + x1 * B[128 + j] + x2 * B[256 + j];
    float sn, cs;
    __sincosf(z, &sn, &cs);
    h[(size_t)b * NHID + j] = cs;
    h[(size_t)b * NHID + 128 + j] = sn;
}

// ------------------------------------------------- weight prepack, quad-chunk frag order
// pw[(((kq*16 + nt)*64 + lane)*4 + c)*8 + j]
//   = bf16( W[nt*16 + (lane&15)][(kq*4+c)*32 + (lane>>4)*8 + j] )
__global__ __launch_bounds__(256) void kan_prepack(
    const float* __restrict__ CU, const float* __restrict__ CV,
    const float* __restrict__ Cin, const float* __restrict__ Cout,
    unsigned short* __restrict__ pw)
{
    int mat = blockIdx.y;   // 0=CU 1=CV 2..5=Cin[i] 6..9=Cout[i]
    const float* src;
    if (mat == 0) src = CU;
    else if (mat == 1) src = CV;
    else if (mat < 6) src = Cin + (size_t)(mat - 2) * MAT_ELEMS;
    else src = Cout + (size_t)(mat - 6) * MAT_ELEMS;
    unsigned short* dst = pw + (size_t)mat * MAT_ELEMS;

    int p8 = blockIdx.x * 256 + threadIdx.x;   // 0..65535 (16B groups)
    int c  = p8 & 3;
    int l  = (p8 >> 2) & 63;
    int nt = (p8 >> 8) & 15;
    int kq = p8 >> 12;
    int o = nt * 16 + (l & 15);
    int k = (kq * 4 + c) * 32 + ((l >> 4) << 3);
    const float* s = src + (size_t)o * KTOT + k;
    short8 v;
#pragma unroll
    for (int j = 0; j < 8; ++j) v[j] = (short)f2bf(s[j]);
    *(short8*)(dst + (size_t)p8 * 8) = v;
}

// ---------------------------------------------------------------- fused KAN GEMM
// 256 threads = 4 waves. Block tile: 64 rows x 128 cols (N-split via blockIdx.y).
// Wave: m 0..63 (mf=4), n = 32 wide (nf=2). 8 basis chunk-buffers in LDS,
// ONE lgkm-only barrier per 4 K-chunks (16 barriers). B frags global->VGPR
// from quad-chunk-packed weights. Coalesced epilogue via LDS transpose.
__global__ __launch_bounds__(256) void kan_gemm(
    const float* __restrict__ act,
    const unsigned short* __restrict__ pw0,
    const unsigned short* __restrict__ pw1,
    float* out0, float* out1,
    const float* __restrict__ ubuf, const float* __restrict__ vbuf,
    const float* idb, const float* __restrict__ scal,
    int mode)
{
    __shared__ __attribute__((aligned(16))) char sm[SMEM_BYTES];
    unsigned short* sm_s = (unsigned short*)sm;

    const int tid = threadIdx.x;
    const int wv = tid >> 6;         // 0..3
    const int lane = tid & 63;
    const int b0 = blockIdx.x * BM;
    const int ns = blockIdx.y;       // N-split half: cols ns*128 ..

    const unsigned short* pw = blockIdx.z ? pw1 : pw0;
    float* outp = blockIdx.z ? out1 : out0;

    f32x4 acc[4][2];
#pragma unroll
    for (int i = 0; i < 4; ++i)
#pragma unroll
        for (int j = 0; j < 2; ++j)
            acc[i][j] = (f32x4){0.f, 0.f, 0.f, 0.f};

    // producer: row = lane, chunk-in-quad = wv. One float4 h load + 4 chebs / superstep.
    const float4* hrow4 = (const float4*)(act + (size_t)(b0 + lane) * NHID);
    // writer base: buf (pb+wv), frag mf=lane>>4, slot bil*16 + (lane&15)
    unsigned short* bw = sm_s + wv * 2048 + (lane >> 4) * 512 + (lane & 15) * 8;
    // reader base: contiguous per lane; buf/mf via immediate offsets
    const unsigned short* ar = sm_s + lane * 8;

    // B fragment pointers: nt0 = ns*8 + wv*2 (each n-tile owned by exactly one wave)
    const int nt0 = ns * 8 + wv * 2;
    const unsigned short* pB0 = pw + (size_t)((nt0 + 0) * 64 + lane) * 32;
    const unsigned short* pB1 = pw + (size_t)((nt0 + 1) * 64 + lane) * 32;

    short8 bfr[4][2];   // current quad's B frags [chunk][nf]
#pragma unroll
    for (int c = 0; c < 4; ++c) {
        bfr[c][0] = *(const short8*)(pB0 + c * 8);
        bfr[c][1] = *(const short8*)(pB1 + c * 8);
    }
    pB0 += QUAD_SHORTS;
    pB1 += QUAD_SHORTS;

    float4 hq = hrow4[wv];           // quad 0
    int hidx = 4 + wv;

#define PRODUCE(PB)                                                     \
    {                                                                   \
        int4v pk0 = cheb_pack(hq.x);                                    \
        int4v pk1 = cheb_pack(hq.y);                                    \
        int4v pk2 = cheb_pack(hq.z);                                    \
        int4v pk3 = cheb_pack(hq.w);                                    \
        unsigned short* wb = bw + (PB) * 2048;                          \
        *(int4v*)(wb)       = pk0;                                      \
        *(int4v*)(wb + 128) = pk1;                                      \
        *(int4v*)(wb + 256) = pk2;                                      \
        *(int4v*)(wb + 384) = pk3;                                      \
        hq = hrow4[hidx & 63]; hidx += 4;                               \
    }

    PRODUCE(0);          // quad 0 -> bufs 0..3
    block_sync_lds();

#define STEP(CB, PB)                                                    \
    {                                                                   \
        short8 af;                                                      \
        _Pragma("unroll")                                               \
        for (int c = 0; c < 4; ++c) {                                   \
            _Pragma("unroll")                                           \
            for (int mf = 0; mf < 4; ++mf) {                            \
                af = *(const short8*)(ar + ((CB + c) * 4 + mf) * 512);  \
                acc[mf][0] = __builtin_amdgcn_mfma_f32_16x16x32_bf16(af, bfr[c][0], acc[mf][0], 0, 0, 0); \
                acc[mf][1] = __builtin_amdgcn_mfma_f32_16x16x32_bf16(af, bfr[c][1], acc[mf][1], 0, 0, 0); \
            }                                                           \
            bfr[c][0] = *(const short8*)(pB0 + c * 8);                  \
            bfr[c][1] = *(const short8*)(pB1 + c * 8);                  \
        }                                                               \
        pB0 += QUAD_SHORTS; pB1 += QUAD_SHORTS;                         \
        PRODUCE(PB);                                                    \
        block_sync_lds();                                               \
    }

#pragma unroll 1
    for (int o = 0; o < 8; ++o) {
        STEP(0, 4);      // consume bufs 0..3, produce next quad -> bufs 4..7
        STEP(4, 0);      // consume bufs 4..7, produce next quad -> bufs 0..3
    }
    // (final iteration's production/prefetch writes junk buffers / reads past
    //  matrix end into adjacent ws allocations — never consumed, harmless)

    // --- epilogue: acc -> LDS (row-major) -> coalesced float4 fuse+store
    float* fs = (float*)sm;
    const int col = lane & 15;
    const int rb = (lane >> 4) * 4;
    float s = 0.f;
    if (mode == 1) s = *scal;
#pragma unroll
    for (int mf = 0; mf < 4; ++mf)
#pragma unroll
        for (int nf = 0; nf < 2; ++nf)
#pragma unroll
            for (int r = 0; r < 4; ++r)
                fs[(mf * 16 + rb + r) * EPI_STRIDE + (wv * 2 + nf) * 16 + col] = acc[mf][nf][r];
    block_sync_lds();

    const int cg = (tid & 31) * 4;       // col group 0..124
    const int r0 = tid >> 5;             // row offset 0..7
#pragma unroll
    for (int it = 0; it < 8; ++it) {
        int row = it * 8 + r0;
        float4 g4 = *(const float4*)&fs[row * EPI_STRIDE + cg];
        size_t idx = (size_t)(b0 + row) * NHID + ns * 128 + cg;
        if (mode == 0) {
            *(float4*)(outp + idx) = g4;
        } else {
            float4 u4 = *(const float4*)(ubuf + idx);
            float4 v4 = *(const float4*)(vbuf + idx);
            float4 i4 = *(const float4*)(idb + idx);
            float4 o4;
            o4.x = s * (v4.x + g4.x * (u4.x - v4.x)) + (1.0f - s) * i4.x;
            o4.y = s * (v4.y + g4.y * (u4.y - v4.y)) + (1.0f - s) * i4.y;
            o4.z = s * (v4.z + g4.z * (u4.z - v4.z)) + (1.0f - s) * i4.z;
            o4.w = s * (v4.w + g4.w * (u4.w - v4.w)) + (1.0f - s) * i4.w;
            *(float4*)(outp + idx) = o4;
        }
    }
#undef STEP
#undef PRODUCE
}

// ---------------------------------------------------------------- final layer (N_OUT=1)
__global__ __launch_bounds__(256) void kan_final(
    const float* __restrict__ h, const float* __restrict__ Cf, float* __restrict__ out)
{
    __shared__ float cf[NHID * 9];
    const int tid = threadIdx.x;
    for (int i = tid; i < KTOT; i += 256)
        cf[(i >> 3) * 9 + (i & 7)] = Cf[i];
    __syncthreads();
    const int wv = tid >> 6, lane = tid & 63;
    const int b0 = blockIdx.x * 64;
#pragma unroll 1
    for (int p = 0; p < 16; ++p) {
        int row = b0 + wv * 16 + p;
        const float* hr = h + (size_t)row * NHID;
        float4 hv = ((const float4*)hr)[lane];
        const float* hvp = (const float*)&hv;
        float a = 0.f;
#pragma unroll
        for (int j = 0; j < 4; ++j) {
            int i = lane * 4 + j;
            float t = fast_tanh(hvp[j]);
            const float* c = &cf[i * 9];
            float accv = c[0] + c[1] * t;
            float t2 = t + t;
            float Tm = 1.0f, Tc = t;
#pragma unroll
            for (int d = 2; d < 8; ++d) {
                float Tn = fmaf(t2, Tc, -Tm);
                accv = fmaf(c[d], Tn, accv);
                Tm = Tc; Tc = Tn;
            }
            a += accv;
        }
#pragma unroll
        for (int off = 32; off > 0; off >>= 1) a += __shfl_down(a, off);
        if (lane == 0) out[row] = a;
    }
}

// ---------------------------------------------------------------- launch
extern "C" void kernel_launch(void* const* d_in, const int* in_sizes, int n_in,
                              void* d_out, int out_size, void* d_ws, size_t ws_size,
                              hipStream_t stream)
{
    const float* x      = (const float*)d_in[0];
    const float* Brff   = (const float*)d_in[1];
    const float* CU     = (const float*)d_in[2];
    const float* CV     = (const float*)d_in[3];
    const float* Cin    = (const float*)d_in[4];
    const float* Cout   = (const float*)d_in[5];
    const float* alphas = (const float*)d_in[6];
    const float* betas  = (const float*)d_in[7];
    const float* Cf     = (const float*)d_in[8];
    float* out = (float*)d_out;

    char* ws = (char*)d_ws;
    const size_t PW_BYTES  = (size_t)10 * MAT_ELEMS * sizeof(unsigned short); // 10.5 MB
    const size_t ACT_BYTES = (size_t)BATCH * NHID * sizeof(float);            // 33.5 MB
    unsigned short* pw = (unsigned short*)ws;
    float* h  = (float*)(ws + PW_BYTES);
    float* u  = (float*)(ws + PW_BYTES + ACT_BYTES);
    float* v  = (float*)(ws + PW_BYTES + 2 * ACT_BYTES);
    float* t1 = (float*)(ws + PW_BYTES + 3 * ACT_BYTES);

    kan_rff<<<BATCH * 128 / 256, 256, 0, stream>>>(x, Brff, h);
    kan_prepack<<<dim3(256, 10), 256, 0, stream>>>(CU, CV, Cin, Cout, pw);

    // u and v fused via blockIdx.z; N-split via blockIdx.y
    kan_gemm<<<dim3(BATCH / BM, 2, 2), 256, 0, stream>>>(
        h, pw, pw + MAT_ELEMS, u, v, nullptr, nullptr, nullptr, nullptr, 0);

    for (int i = 0; i < 4; ++i) {
        const unsigned short* pwIn  = pw + (size_t)(2 + i) * MAT_ELEMS;
        const unsigned short* pwOut = pw + (size_t)(6 + i) * MAT_ELEMS;
        kan_gemm<<<dim3(BATCH / BM, 2, 1), 256, 0, stream>>>(
            h, pwIn, nullptr, t1, nullptr, u, v, h, betas + i, 1);
        kan_gemm<<<dim3(BATCH / BM, 2, 1), 256, 0, stream>>>(
            t1, pwOut, nullptr, h, nullptr, u, v, h, alphas + i, 1);
    }

    kan_final<<<BATCH / 64, 256, 0, stream>>>(h, Cf, out);
}